// Round 1
// 224.535 us; speedup vs baseline: 1.0052x; 1.0052x over previous
//
#include <hip/hip_runtime.h>
#include <math.h>

#define TPB 256
#define EPT 2   // batch elements per thread, lane-strided by TPB for coalescing

// Per-row gas-net table: NETS[r][s] = net id of species s contributing to row r,
// 255 = species absent. Species s: 0=h2o 1=h2o_sq 2=o3 3=co2 4=n2o 5=ch4 6=u.
// Net id spaces: h2o 0..22 (via H2O_IDX), h2o_sq 23..51, o3 52..64, co2 65..73,
// n2o 74..76, ch4 77..85, u 86..98. Row padded to 8 for alignment.
static __device__ const unsigned char NETS[29][8] = {
    {  0, 23,  52,  65,  74,  77,  86, 255},
    {  1, 24,  53,  66,  75,  78,  87, 255},
    {  2, 25,  54,  67,  76,  79,  88, 255},
    {  3, 26, 255, 255, 255,  80, 255, 255},
    {  4, 27, 255, 255, 255,  81, 255, 255},
    {  5, 28, 255,  68, 255, 255, 255, 255},
    {  6, 29, 255,  69, 255, 255, 255, 255},
    {  3, 30, 255, 255, 255,  82, 255, 255},   // h2o idx 3 reused
    {  4, 31, 255, 255, 255,  83, 255, 255},   // h2o idx 4 reused
    {  9, 32, 255,  70, 255, 255, 255, 255},
    { 10, 33, 255,  71, 255, 255, 255, 255},
    { 11, 34, 255, 255, 255,  84, 255, 255},
    { 12, 35, 255, 255, 255,  85, 255, 255},
    { 13, 36, 255,  72, 255, 255, 255, 255},
    { 14, 37, 255,  73, 255, 255, 255, 255},
    { 15, 38, 255, 255, 255, 255,  89, 255},
    { 16, 39, 255, 255, 255, 255,  90, 255},
    { 17, 40,  55, 255, 255, 255,  91, 255},
    { 18, 41,  56, 255, 255, 255,  92, 255},
    { 19, 42,  57, 255, 255, 255,  93, 255},
    { 20, 43,  58, 255, 255, 255,  94, 255},
    { 21, 44,  59, 255, 255, 255,  95, 255},
    { 22, 45,  60, 255, 255, 255,  96, 255},
    {255, 46, 255, 255, 255, 255, 255, 255},
    {255, 47, 255, 255, 255, 255, 255, 255},
    {255, 48,  61, 255, 255, 255, 255, 255},
    {255, 49,  62, 255, 255, 255, 255, 255},
    {255, 50,  63, 255, 255, 255,  97, 255},
    {255, 51,  64, 255, 255, 255,  98, 255}};

__device__ __forceinline__ float elu1(float h) {
    return h > 0.f ? h : (__expf(h) - 1.f);
}

__device__ __forceinline__ float fast_rcp(float x) {
    return __builtin_amdgcn_rcpf(x);
}

__device__ __forceinline__ void softmax3_store(float o0, float o1, float o2,
                                               float* __restrict__ dst) {
    o0 = fmaxf(o0, 0.f);
    o1 = fmaxf(o1, 0.f);
    o2 = fmaxf(o2, 0.f);
    const float mx = fmaxf(o0, fmaxf(o1, o2));
    const float e0 = __expf(o0 - mx);
    const float e1 = __expf(o1 - mx);
    const float e2 = __expf(o2 - mx);
    const float rs = fast_rcp(e0 + e1 + e2);
    dst[0] = e0 * rs;
    dst[1] = e1 * rs;
    dst[2] = e2 * rs;
}

__global__ __launch_bounds__(TPB) void atm_kernel(
    const float* __restrict__ temp,
    const float* __restrict__ pressure,
    const float* __restrict__ c_h2o,
    const float* __restrict__ c_h2o_sq,
    const float* __restrict__ c_o3,
    const float* __restrict__ c_co2,
    const float* __restrict__ c_n2o,
    const float* __restrict__ c_ch4,
    const float* __restrict__ c_u,
    const float* __restrict__ lwp,
    const float* __restrict__ iwp,
    const float* __restrict__ mu,
    const float* __restrict__ mu_bar,
    const float* __restrict__ gW1,   // (99,2,8)  [n*16 + i*8 + h]
    const float* __restrict__ gb1,   // (99,8)
    const float* __restrict__ gW2,   // (99,8,1)
    const float* __restrict__ gb2,   // (99,1)
    const float* __restrict__ lw_w,  // (29,1)
    const float* __restrict__ iw_w,  // (29,1)
    const float* __restrict__ eW1,   // (29,4,16) [r*64 + i*16 + j]
    const float* __restrict__ eb1,   // (29,16)
    const float* __restrict__ eW2,   // (29,16,3) [r*48 + j*3 + k]
    const float* __restrict__ eb2,   // (29,3)
    float* __restrict__ out,
    int Bn)
{
    const int r = blockIdx.x;                             // wave-uniform row 0..28
    const int base = blockIdx.y * (TPB * EPT) + threadIdx.x;
    if (base >= Bn) return;
    const int bA = base;
    const int bB = base + TPB;
    const bool vB = (bB < Bn);
    const int bBl = vB ? bB : bA;                         // clamped load index

    // ---- per-batch inputs for both elements ----
    const float tA = temp[bA],       tB = temp[bBl];
    const float pA = pressure[bA],   pB = pressure[bBl];
    float cA[7], cB[7];
    cA[0] = c_h2o[bA];     cB[0] = c_h2o[bBl];
    cA[1] = c_h2o_sq[bA];  cB[1] = c_h2o_sq[bBl];
    cA[2] = c_o3[bA];      cB[2] = c_o3[bBl];
    cA[3] = c_co2[bA];     cB[3] = c_co2[bBl];
    cA[4] = c_n2o[bA];     cB[4] = c_n2o[bBl];
    cA[5] = c_ch4[bA];     cB[5] = c_ch4[bBl];
    cA[6] = c_u[bA];       cB[6] = c_u[bBl];
    const float lwpA = lwp[bA],    lwpB = lwp[bBl];
    const float iwpA = iwp[bA],    iwpB = iwp[bBl];
    const float muA  = mu[bA],     muB  = mu[bBl];
    const float mbA  = mu_bar[bA], mbB  = mu_bar[bBl];

    // ---- gas nets: fully-unrolled species loop, static comp index ----
    float tgA = 0.f, tgB = 0.f;
    #pragma unroll
    for (int s = 0; s < 7; ++s) {
        const int n = NETS[r][s];                 // uniform
        if (n != 255) {
            const float4* W1 = (const float4*)(gW1 + (n << 4));
            const float4 wt0 = W1[0], wt1 = W1[1];     // t-weights j=0..3, 4..7
            const float4 wp0 = W1[2], wp1 = W1[3];     // p-weights
            const float4* B1 = (const float4*)(gb1 + (n << 3));
            const float4 bb0 = B1[0], bb1 = B1[1];
            const float4* W2 = (const float4*)(gW2 + (n << 3));
            const float4 wo0 = W2[0], wo1 = W2[1];
            const float bias = gb2[n];
            float aA = bias, aB = bias;
#define GAS_H(WT, WP, BB, WO, K)                                        \
            { float hA = fmaf(tA, (WT).K, fmaf(pA, (WP).K, (BB).K));    \
              float hB = fmaf(tB, (WT).K, fmaf(pB, (WP).K, (BB).K));    \
              hA = elu1(hA); hB = elu1(hB);                             \
              aA = fmaf(hA, (WO).K, aA); aB = fmaf(hB, (WO).K, aB); }
            GAS_H(wt0, wp0, bb0, wo0, x)
            GAS_H(wt0, wp0, bb0, wo0, y)
            GAS_H(wt0, wp0, bb0, wo0, z)
            GAS_H(wt0, wp0, bb0, wo0, w)
            GAS_H(wt1, wp1, bb1, wo1, x)
            GAS_H(wt1, wp1, bb1, wo1, y)
            GAS_H(wt1, wp1, bb1, wo1, z)
            GAS_H(wt1, wp1, bb1, wo1, w)
#undef GAS_H
            aA = fmaxf(aA, 0.f);                       // ReLU -> ke
            aB = fmaxf(aB, 0.f);
            tgA = fmaf(aA, cA[s], tgA);                // s is compile-time here
            tgB = fmaf(aB, cB[s], tgB);
        }
    }

    // ---- tau composition ----
    const float lwr = lw_w[r], iwr = iw_w[r];          // uniform
    const float tlwA = lwr * lwpA, tlwB = lwr * lwpB;
    const float tiwA = iwr * iwpA, tiwB = iwr * iwpB;
    const float ttA = tgA + tlwA + tiwA;
    const float ttB = tgB + tlwB + tiwB;
    const float rttA = fast_rcp(ttA);
    const float rttB = fast_rcp(ttB);
    const float in1A = tlwA * rttA, in2A = tiwA * rttA;
    const float in1B = tlwB * rttB, in2B = tiwB * rttB;
    const float i3dA = ttA * fast_rcp(muA);
    const float i3fA = ttA * fast_rcp(mbA);
    const float i3dB = ttB * fast_rcp(muB);
    const float i3fB = ttB * fast_rcp(mbB);

    const size_t idxA = (size_t)r * (size_t)Bn + (size_t)bA;
    out[idxA] = __expf(-i3dA);                          // t_direct
    out[(size_t)29 * Bn + idxA] = __expf(-i3fA);        // t_diffuse
    if (vB) {
        out[idxA + TPB] = __expf(-i3dB);
        out[(size_t)29 * Bn + idxA + TPB] = __expf(-i3fB);
    }

    // ---- extinction net (row r): 2 elements x 2 passes, shared weights,
    //      shared (in1,in2,b1) partial sum across passes ----
    const float* w1  = eW1 + (r << 6);
    const float* ebv = eb1 + (r << 4);
    const float* w2  = eW2 + r * 48;
    const float bo0 = eb2[r * 3 + 0];
    const float bo1 = eb2[r * 3 + 1];
    const float bo2 = eb2[r * 3 + 2];

    float dA0 = bo0, dA1 = bo1, dA2 = bo2;   // elem A, direct
    float fA0 = bo0, fA1 = bo1, fA2 = bo2;   // elem A, diffuse
    float dB0 = bo0, dB1 = bo1, dB2 = bo2;   // elem B, direct
    float fB0 = bo0, fB1 = bo1, fB2 = bo2;   // elem B, diffuse

    #pragma unroll
    for (int q = 0; q < 4; ++q) {
        const float4 wA4 = *(const float4*)(w1 + 4 * q);        // in1 weights
        const float4 wB4 = *(const float4*)(w1 + 16 + 4 * q);   // in2 weights
        const float4 wC4 = *(const float4*)(w1 + 32 + 4 * q);   // in3 weights
        const float4 wD4 = *(const float4*)(w1 + 48 + 4 * q);   // mu  weights
        const float4 bj4 = *(const float4*)(ebv + 4 * q);
        const float4 u0  = *(const float4*)(w2 + 12 * q);       // W2 rows j..j+3
        const float4 u1  = *(const float4*)(w2 + 12 * q + 4);
        const float4 u2  = *(const float4*)(w2 + 12 * q + 8);
#define EXT_H(K, W20, W21, W22)                                               \
        { const float bsA = fmaf(in1A, (wA4).K, fmaf(in2A, (wB4).K, (bj4).K)); \
          const float bsB = fmaf(in1B, (wA4).K, fmaf(in2B, (wB4).K, (bj4).K)); \
          const float hdA = elu1(fmaf(i3dA, (wC4).K, fmaf(muA, (wD4).K, bsA))); \
          const float hfA = elu1(fmaf(i3fA, (wC4).K, fmaf(mbA, (wD4).K, bsA))); \
          const float hdB = elu1(fmaf(i3dB, (wC4).K, fmaf(muB, (wD4).K, bsB))); \
          const float hfB = elu1(fmaf(i3fB, (wC4).K, fmaf(mbB, (wD4).K, bsB))); \
          dA0 = fmaf(hdA, (W20), dA0); dA1 = fmaf(hdA, (W21), dA1); dA2 = fmaf(hdA, (W22), dA2); \
          fA0 = fmaf(hfA, (W20), fA0); fA1 = fmaf(hfA, (W21), fA1); fA2 = fmaf(hfA, (W22), fA2); \
          dB0 = fmaf(hdB, (W20), dB0); dB1 = fmaf(hdB, (W21), dB1); dB2 = fmaf(hdB, (W22), dB2); \
          fB0 = fmaf(hfB, (W20), fB0); fB1 = fmaf(hfB, (W21), fB1); fB2 = fmaf(hfB, (W22), fB2); }
        EXT_H(x, u0.x, u0.y, u0.z)
        EXT_H(y, u0.w, u1.x, u1.y)
        EXT_H(z, u1.z, u1.w, u2.x)
        EXT_H(w, u2.y, u2.z, u2.w)
#undef EXT_H
    }

    // ---- softmax + stores ----
    float* pdA = out + (size_t)58 * Bn + idxA * 3;      // e_direct  (29,B,3)
    float* pfA = out + (size_t)145 * Bn + idxA * 3;     // e_diffuse (29,B,3)
    softmax3_store(dA0, dA1, dA2, pdA);
    softmax3_store(fA0, fA1, fA2, pfA);
    if (vB) {
        float* pdB = out + (size_t)58 * Bn + (idxA + TPB) * 3;
        float* pfB = out + (size_t)145 * Bn + (idxA + TPB) * 3;
        softmax3_store(dB0, dB1, dB2, pdB);
        softmax3_store(fB0, fB1, fB2, pfB);
    }
}

extern "C" void kernel_launch(void* const* d_in, const int* in_sizes, int n_in,
                              void* d_out, int out_size, void* d_ws, size_t ws_size,
                              hipStream_t stream) {
    const int Bn = in_sizes[0];  // temp has B elements
    dim3 grid(29, (Bn + TPB * EPT - 1) / (TPB * EPT));
    atm_kernel<<<grid, TPB, 0, stream>>>(
        (const float*)d_in[0],  (const float*)d_in[1],  (const float*)d_in[2],
        (const float*)d_in[3],  (const float*)d_in[4],  (const float*)d_in[5],
        (const float*)d_in[6],  (const float*)d_in[7],  (const float*)d_in[8],
        (const float*)d_in[9],  (const float*)d_in[10], (const float*)d_in[11],
        (const float*)d_in[12], (const float*)d_in[13], (const float*)d_in[14],
        (const float*)d_in[15], (const float*)d_in[16], (const float*)d_in[17],
        (const float*)d_in[18], (const float*)d_in[19], (const float*)d_in[20],
        (const float*)d_in[21], (const float*)d_in[22],
        (float*)d_out, Bn);
}

// Round 2
// 207.192 us; speedup vs baseline: 1.0893x; 1.0837x over previous
//
#include <hip/hip_runtime.h>
#include <math.h>

#define TPB 256
#define EPT 2   // batch elements per thread: b and b+TPB (coalesced pair)

typedef float v2f __attribute__((ext_vector_type(2)));

#define VFMA(a, b, c) __builtin_elementwise_fma((a), (b), (c))
#define VMAX(a, b) __builtin_elementwise_max((a), (b))
#define LOG2E 1.4426950408889634f

static __device__ __forceinline__ v2f sp(float s) { return (v2f){s, s}; }

static __device__ __forceinline__ float fexp2(float x) {
#if __has_builtin(__builtin_amdgcn_exp2f)
    return __builtin_amdgcn_exp2f(x);
#else
    return __expf(x * 0.6931471805599453f);
#endif
}

static __device__ __forceinline__ float fast_rcp(float x) {
    return __builtin_amdgcn_rcpf(x);
}

// ELU on a packed A/B pair: pk_mul + 2x v_exp + pk_add + 2x cndmask
static __device__ __forceinline__ v2f elu2(v2f h) {
    v2f t = h * LOG2E;                       // v_pk_mul_f32
    v2f e = {fexp2(t.x), fexp2(t.y)};        // quarter-rate, unpackable
    e = e - 1.0f;                            // v_pk_add_f32
    return (v2f){h.x > 0.f ? h.x : e.x, h.y > 0.f ? h.y : e.y};
}

// Per-row gas-net table: NETS[r][s] = net id of species s contributing to row r,
// 255 = absent. Species s: 0=h2o 1=h2o_sq 2=o3 3=co2 4=n2o 5=ch4 6=u.
static __device__ const unsigned char NETS[29][8] = {
    {  0, 23,  52,  65,  74,  77,  86, 255},
    {  1, 24,  53,  66,  75,  78,  87, 255},
    {  2, 25,  54,  67,  76,  79,  88, 255},
    {  3, 26, 255, 255, 255,  80, 255, 255},
    {  4, 27, 255, 255, 255,  81, 255, 255},
    {  5, 28, 255,  68, 255, 255, 255, 255},
    {  6, 29, 255,  69, 255, 255, 255, 255},
    {  3, 30, 255, 255, 255,  82, 255, 255},
    {  4, 31, 255, 255, 255,  83, 255, 255},
    {  9, 32, 255,  70, 255, 255, 255, 255},
    { 10, 33, 255,  71, 255, 255, 255, 255},
    { 11, 34, 255, 255, 255,  84, 255, 255},
    { 12, 35, 255, 255, 255,  85, 255, 255},
    { 13, 36, 255,  72, 255, 255, 255, 255},
    { 14, 37, 255,  73, 255, 255, 255, 255},
    { 15, 38, 255, 255, 255, 255,  89, 255},
    { 16, 39, 255, 255, 255, 255,  90, 255},
    { 17, 40,  55, 255, 255, 255,  91, 255},
    { 18, 41,  56, 255, 255, 255,  92, 255},
    { 19, 42,  57, 255, 255, 255,  93, 255},
    { 20, 43,  58, 255, 255, 255,  94, 255},
    { 21, 44,  59, 255, 255, 255,  95, 255},
    { 22, 45,  60, 255, 255, 255,  96, 255},
    {255, 46, 255, 255, 255, 255, 255, 255},
    {255, 47, 255, 255, 255, 255, 255, 255},
    {255, 48,  61, 255, 255, 255, 255, 255},
    {255, 49,  62, 255, 255, 255, 255, 255},
    {255, 50,  63, 255, 255, 255,  97, 255},
    {255, 51,  64, 255, 255, 255,  98, 255}};

// packed softmax over 3 logits for the A/B pair
static __device__ __forceinline__ void softmax3_v2(v2f o0, v2f o1, v2f o2,
                                                   v2f& r0, v2f& r1, v2f& r2) {
    o0 = VMAX(o0, sp(0.f));                  // ReLU
    o1 = VMAX(o1, sp(0.f));
    o2 = VMAX(o2, sp(0.f));
    v2f mx = VMAX(o0, VMAX(o1, o2));
    v2f nm = mx * (-LOG2E);                  // pk_mul
    v2f a0 = VFMA(o0, sp(LOG2E), nm);        // (o-mx)*log2e as pk_fma
    v2f a1 = VFMA(o1, sp(LOG2E), nm);
    v2f a2 = VFMA(o2, sp(LOG2E), nm);
    v2f e0 = {fexp2(a0.x), fexp2(a0.y)};
    v2f e1 = {fexp2(a1.x), fexp2(a1.y)};
    v2f e2 = {fexp2(a2.x), fexp2(a2.y)};
    v2f ssum = e0 + e1 + e2;                 // 2x pk_add
    v2f rs = {fast_rcp(ssum.x), fast_rcp(ssum.y)};
    r0 = e0 * rs; r1 = e1 * rs; r2 = e2 * rs;
}

template <bool GUARD>
__global__ __launch_bounds__(TPB) void atm_kernel(
    const float* __restrict__ temp,
    const float* __restrict__ pressure,
    const float* __restrict__ c_h2o,
    const float* __restrict__ c_h2o_sq,
    const float* __restrict__ c_o3,
    const float* __restrict__ c_co2,
    const float* __restrict__ c_n2o,
    const float* __restrict__ c_ch4,
    const float* __restrict__ c_u,
    const float* __restrict__ lwp,
    const float* __restrict__ iwp,
    const float* __restrict__ mu,
    const float* __restrict__ mu_bar,
    const float* __restrict__ gW1,   // (99,2,8)  [n*16 + i*8 + h]
    const float* __restrict__ gb1,   // (99,8)
    const float* __restrict__ gW2,   // (99,8,1)
    const float* __restrict__ gb2,   // (99,1)
    const float* __restrict__ lw_w,  // (29,1)
    const float* __restrict__ iw_w,  // (29,1)
    const float* __restrict__ eW1,   // (29,4,16) [r*64 + i*16 + j]
    const float* __restrict__ eb1,   // (29,16)
    const float* __restrict__ eW2,   // (29,16,3) [r*48 + j*3 + k]
    const float* __restrict__ eb2,   // (29,3)
    float* __restrict__ out,
    int Bn)
{
    const int r = blockIdx.x;                             // uniform row 0..28
    const int bA = blockIdx.y * (TPB * EPT) + threadIdx.x;
    if (GUARD && bA >= Bn) return;
    const int bB = bA + TPB;
    bool vB = true;
    int bBl = bB;
    if (GUARD) { vB = (bB < Bn); bBl = vB ? bB : bA; }

    // ---- packed per-batch inputs: .x = elem A, .y = elem B ----
    const v2f t2  = {temp[bA],     temp[bBl]};
    const v2f p2  = {pressure[bA], pressure[bBl]};
    v2f comp2[7];
    comp2[0] = (v2f){c_h2o[bA],    c_h2o[bBl]};
    comp2[1] = (v2f){c_h2o_sq[bA], c_h2o_sq[bBl]};
    comp2[2] = (v2f){c_o3[bA],     c_o3[bBl]};
    comp2[3] = (v2f){c_co2[bA],    c_co2[bBl]};
    comp2[4] = (v2f){c_n2o[bA],    c_n2o[bBl]};
    comp2[5] = (v2f){c_ch4[bA],    c_ch4[bBl]};
    comp2[6] = (v2f){c_u[bA],      c_u[bBl]};
    const v2f lwp2 = {lwp[bA],    lwp[bBl]};
    const v2f iwp2 = {iwp[bA],    iwp[bBl]};
    const v2f mu2  = {mu[bA],     mu[bBl]};
    const v2f mb2  = {mu_bar[bA], mu_bar[bBl]};

    // ---- gas nets (packed A/B), fully-unrolled species loop ----
    v2f tg = sp(0.f);
    #pragma unroll
    for (int s = 0; s < 7; ++s) {
        const int n = NETS[r][s];                 // uniform -> scalar branch
        if (n != 255) {
            const float4* W1 = (const float4*)(gW1 + (n << 4));
            const float4 wt0 = W1[0], wt1 = W1[1];     // temp weights j=0..7
            const float4 wp0 = W1[2], wp1 = W1[3];     // pressure weights
            const float4* B1 = (const float4*)(gb1 + (n << 3));
            const float4 bb0 = B1[0], bb1 = B1[1];
            const float4* W2 = (const float4*)(gW2 + (n << 3));
            const float4 wo0 = W2[0], wo1 = W2[1];
            v2f acc = sp(gb2[n]);
#define GAS_H(WT, WP, BB, WO, K)                                            \
            { v2f h = VFMA(t2, sp((WT).K), VFMA(p2, sp((WP).K), sp((BB).K))); \
              h = elu2(h);                                                   \
              acc = VFMA(h, sp((WO).K), acc); }
            GAS_H(wt0, wp0, bb0, wo0, x)
            GAS_H(wt0, wp0, bb0, wo0, y)
            GAS_H(wt0, wp0, bb0, wo0, z)
            GAS_H(wt0, wp0, bb0, wo0, w)
            GAS_H(wt1, wp1, bb1, wo1, x)
            GAS_H(wt1, wp1, bb1, wo1, y)
            GAS_H(wt1, wp1, bb1, wo1, z)
            GAS_H(wt1, wp1, bb1, wo1, w)
#undef GAS_H
            acc = VMAX(acc, sp(0.f));              // ReLU -> ke
            tg = VFMA(acc, comp2[s], tg);
        }
    }

    // ---- tau composition (packed) ----
    const float lwr = lw_w[r], iwr = iw_w[r];      // uniform
    v2f tlw = lwp2 * lwr;
    v2f tiw = iwp2 * iwr;
    v2f tt = tg + tlw + tiw;
    v2f rtt = {fast_rcp(tt.x), fast_rcp(tt.y)};
    v2f in1 = tlw * rtt;
    v2f in2 = tiw * rtt;
    v2f rmu = {fast_rcp(mu2.x), fast_rcp(mu2.y)};
    v2f rmb = {fast_rcp(mb2.x), fast_rcp(mb2.y)};
    v2f i3d = tt * rmu;
    v2f i3f = tt * rmb;

    const int idxA = r * Bn + bA;                  // fits int32
    {
        v2f ad = i3d * (-LOG2E);
        v2f af = i3f * (-LOG2E);
        out[idxA] = fexp2(ad.x);                   // t_direct, elem A
        out[29 * Bn + idxA] = fexp2(af.x);         // t_diffuse, elem A
        if (vB) {
            out[idxA + TPB] = fexp2(ad.y);
            out[29 * Bn + idxA + TPB] = fexp2(af.y);
        }
    }

    // ---- extinction net (row r): packed A/B, direct+diffuse share base ----
    const float* w1  = eW1 + (r << 6);
    const float* ebv = eb1 + (r << 4);
    const float* w2  = eW2 + r * 48;
    const float bo0 = eb2[r * 3 + 0];
    const float bo1 = eb2[r * 3 + 1];
    const float bo2 = eb2[r * 3 + 2];

    v2f d0 = sp(bo0), d1 = sp(bo1), d2 = sp(bo2);  // direct logits
    v2f f0 = sp(bo0), f1 = sp(bo1), f2 = sp(bo2);  // diffuse logits

    #pragma unroll
    for (int q = 0; q < 4; ++q) {
        const float4 wA4 = *(const float4*)(w1 + 4 * q);        // in1 weights
        const float4 wB4 = *(const float4*)(w1 + 16 + 4 * q);   // in2 weights
        const float4 wC4 = *(const float4*)(w1 + 32 + 4 * q);   // in3 weights
        const float4 wD4 = *(const float4*)(w1 + 48 + 4 * q);   // mu  weights
        const float4 bj4 = *(const float4*)(ebv + 4 * q);
        const float4 u0  = *(const float4*)(w2 + 12 * q);       // W2 rows
        const float4 u1  = *(const float4*)(w2 + 12 * q + 4);
        const float4 u2  = *(const float4*)(w2 + 12 * q + 8);
#define EXT_H(K, W20, W21, W22)                                               \
        { v2f bs = VFMA(in1, sp((wA4).K), VFMA(in2, sp((wB4).K), sp((bj4).K))); \
          v2f hd = elu2(VFMA(i3d, sp((wC4).K), VFMA(mu2, sp((wD4).K), bs)));   \
          v2f hf = elu2(VFMA(i3f, sp((wC4).K), VFMA(mb2, sp((wD4).K), bs)));   \
          d0 = VFMA(hd, sp(W20), d0); d1 = VFMA(hd, sp(W21), d1);              \
          d2 = VFMA(hd, sp(W22), d2);                                          \
          f0 = VFMA(hf, sp(W20), f0); f1 = VFMA(hf, sp(W21), f1);              \
          f2 = VFMA(hf, sp(W22), f2); }
        EXT_H(x, u0.x, u0.y, u0.z)
        EXT_H(y, u0.w, u1.x, u1.y)
        EXT_H(z, u1.z, u1.w, u2.x)
        EXT_H(w, u2.y, u2.z, u2.w)
#undef EXT_H
    }

    // ---- softmax + stores ----
    v2f r0, r1, r2;
    softmax3_v2(d0, d1, d2, r0, r1, r2);
    float* pdA = out + 58 * Bn + idxA * 3;         // e_direct (29,B,3)
    pdA[0] = r0.x; pdA[1] = r1.x; pdA[2] = r2.x;
    if (vB) {
        float* pdB = pdA + 3 * TPB;
        pdB[0] = r0.y; pdB[1] = r1.y; pdB[2] = r2.y;
    }
    softmax3_v2(f0, f1, f2, r0, r1, r2);
    float* pfA = out + 145 * Bn + idxA * 3;        // e_diffuse (29,B,3)
    pfA[0] = r0.x; pfA[1] = r1.x; pfA[2] = r2.x;
    if (vB) {
        float* pfB = pfA + 3 * TPB;
        pfB[0] = r0.y; pfB[1] = r1.y; pfB[2] = r2.y;
    }
}

extern "C" void kernel_launch(void* const* d_in, const int* in_sizes, int n_in,
                              void* d_out, int out_size, void* d_ws, size_t ws_size,
                              hipStream_t stream) {
    const int Bn = in_sizes[0];  // temp has B elements
    const int span = TPB * EPT;
    dim3 grid(29, (Bn + span - 1) / span);
    if (Bn % span == 0) {
        atm_kernel<false><<<grid, TPB, 0, stream>>>(
            (const float*)d_in[0],  (const float*)d_in[1],  (const float*)d_in[2],
            (const float*)d_in[3],  (const float*)d_in[4],  (const float*)d_in[5],
            (const float*)d_in[6],  (const float*)d_in[7],  (const float*)d_in[8],
            (const float*)d_in[9],  (const float*)d_in[10], (const float*)d_in[11],
            (const float*)d_in[12], (const float*)d_in[13], (const float*)d_in[14],
            (const float*)d_in[15], (const float*)d_in[16], (const float*)d_in[17],
            (const float*)d_in[18], (const float*)d_in[19], (const float*)d_in[20],
            (const float*)d_in[21], (const float*)d_in[22],
            (float*)d_out, Bn);
    } else {
        atm_kernel<true><<<grid, TPB, 0, stream>>>(
            (const float*)d_in[0],  (const float*)d_in[1],  (const float*)d_in[2],
            (const float*)d_in[3],  (const float*)d_in[4],  (const float*)d_in[5],
            (const float*)d_in[6],  (const float*)d_in[7],  (const float*)d_in[8],
            (const float*)d_in[9],  (const float*)d_in[10], (const float*)d_in[11],
            (const float*)d_in[12], (const float*)d_in[13], (const float*)d_in[14],
            (const float*)d_in[15], (const float*)d_in[16], (const float*)d_in[17],
            (const float*)d_in[18], (const float*)d_in[19], (const float*)d_in[20],
            (const float*)d_in[21], (const float*)d_in[22],
            (float*)d_out, Bn);
    }
}